// Round 11
// baseline (8511.630 us; speedup 1.0000x reference)
//
#include <hip/hip_runtime.h>
#include <hip/hip_bf16.h>
#include <hip/hip_fp16.h>
#include <math.h>

// ---------------------------------------------------------------------------
// Seq2Seq (bi-LSTM encoder x2 + fixed-state decoder), B=64 T=1024 H=256.
// Round 11: MFMA dot + IN-LANE cell (no gate exchange, ONE barrier/step).
//  * M re-partition: wave wv owns rows {g*256 + wv*32 + [0,32)} for ALL 4
//    gates (8 M-tiles: (g,hf) g=0..3, hf=0..1). After MFMA each lane holds
//    gi,gf,gg,go for 8 full columns (C-map row=(lane>>4)*4+reg, validated
//    round 10) -> cell fully in-register, redundant across the 16 lane-cols.
//  * h written by lr==0 lanes (packed uint2), double-buffered; 1 barrier.
//  * E1 GW staged one step ahead into 2KB x2 LDS (dead PREWf region) ->
//    same single barrier covers it.
//  * Deferred y0 store (round 9), conflict-free LDS everywhere (round 10).
//  * Producer/R/decoder phases unchanged.
// ---------------------------------------------------------------------------

#define NWG 256
#define THR 512
#define U0S 132      // R-phase A-tile stride in uints

// ws layout (float offsets); first 2048 floats = barrier counters (8 KB)
#define ECL0   2048                 // enc l0 final c (fp32): [dir*16384 + b*256 + k]
#define EHL1   (ECL0 + 32768)       // enc l1 final h packed fp16: uint[dir*8192 + b*128 + p]
#define ECL1   (EHL1 + 16384)       // enc l1 final c (fp32)
#define ROF    (ECL1 + 32768)       // decoder R consts (fp32): [m*65536 + b*1024 + r]
#define WIH1T  (ROF + 262144)       // transposed fp16 eWih1: uint4[dir*65536 + kc*1024 + row]
#define GWR    (WIH1T + 524288)     // GW ring: uint[chain*8192 + slot*4096 + s*512 + g]
#define PCF    (GWR + 1048576)      // flags: uint[chain*64]=produced, [chain*64+32]=consumed
#define Y0OF   (PCF + 8192)         // packed fp16 y0: uint[t*16384 + b*256 + dir*128 + p]
#define WS_REQ_BYTES ((size_t)(Y0OF + 16777216) * 4)   // ~71.4 MB (unchanged)

struct SeqParams {
  const void *x, *eWih0, *eWhh0, *eB0, *eWih1, *eWhh1, *eB1;
  const void *dWih0, *dWhh0, *dB0, *dWih1, *dWhh1, *dB1, *fcW, *fcb;
  void* out;
  float* ws;
  unsigned* ctrs;
};

typedef _Float16 hlf2 __attribute__((ext_vector_type(2)));
typedef _Float16 half8 __attribute__((ext_vector_type(8)));
typedef float floatx4 __attribute__((ext_vector_type(4)));

__device__ __forceinline__ float bf2f(unsigned short u) {
  return __uint_as_float(((unsigned)u) << 16);
}
__device__ __forceinline__ float hf2f(unsigned short u) {
  __half_raw r; r.x = u; return __half2float(__half(r));
}
__device__ __forceinline__ unsigned short f2h_u(float f) {
  __half h = __float2half(f);
  return *reinterpret_cast<unsigned short*>(&h);
}

// ---- fast branch-free transcendentals --------------------------------------
__device__ __forceinline__ float fexp2(float x) {
#if __has_builtin(__builtin_amdgcn_exp2f)
  return __builtin_amdgcn_exp2f(x);
#else
  return exp2f(x);
#endif
}
__device__ __forceinline__ float frcp(float x) {
#if __has_builtin(__builtin_amdgcn_rcpf)
  return __builtin_amdgcn_rcpf(x);
#else
  return 1.0f / x;
#endif
}
__device__ __forceinline__ float sigm(float v) {
  return frcp(1.0f + fexp2(v * -1.44269504f));
}
__device__ __forceinline__ float ftanh(float v) {
  return fmaf(-2.0f, frcp(1.0f + fexp2(v * 2.88539008f)), 1.0f);
}

#if __has_builtin(__builtin_amdgcn_fdot2)
__device__ __forceinline__ float fdot2(hlf2 a, hlf2 b, float c) {
  return __builtin_amdgcn_fdot2(a, b, c, false);
}
#else
__device__ __forceinline__ float fdot2(hlf2 a, hlf2 b, float c) {
  return c + (float)a[0] * (float)b[0] + (float)a[1] * (float)b[1];
}
#endif

__device__ __forceinline__ float dot1(float a, const uint4& x, const uint4& y) {
  const hlf2* xp = reinterpret_cast<const hlf2*>(&x);
  const hlf2* yp = reinterpret_cast<const hlf2*>(&y);
  a = fdot2(xp[0], yp[0], a);
  a = fdot2(xp[1], yp[1], a);
  a = fdot2(xp[2], yp[2], a);
  a = fdot2(xp[3], yp[3], a);
  return a;
}
__device__ __forceinline__ void dot2acc(float4& a, const uint4& hv, const uint4& wv) {
  const hlf2* hp = reinterpret_cast<const hlf2*>(&hv);
  const hlf2* wp = reinterpret_cast<const hlf2*>(&wv);
  a.x = fdot2(hp[0], wp[0], a.x);
  a.y = fdot2(hp[1], wp[1], a.y);
  a.z = fdot2(hp[2], wp[2], a.z);
  a.w = fdot2(hp[3], wp[3], a.w);
}

// MFMA 16x16x32 f16: D = A*B + C (fp32 accumulate)
__device__ __forceinline__ floatx4 mfma16(uint4 a, uint4 b, floatx4 c) {
  union { uint4 u; half8 h; } ua, ub;
  ua.u = a; ub.u = b;
  return __builtin_amdgcn_mfma_f32_16x16x32_f16(ua.h, ub.h, c, 0, 0, 0);
}

__device__ __forceinline__ float ldin(const void* p_, size_t i, int bf) {
  return bf ? bf2f(((const unsigned short*)p_)[i]) : ((const float*)p_)[i];
}
__device__ __forceinline__ void stout(void* o, size_t i, float v, int bf) {
  if (bf) ((__hip_bfloat16*)o)[i] = __float2bfloat16(v);
  else    ((float*)o)[i] = v;
}

__device__ __forceinline__ int detect_bf16(const void* xp) {
  const unsigned* u = (const unsigned*)xp;
  int votes = 0;
#pragma unroll 8
  for (int i = 0; i < 64; ++i) {
    unsigned e = (u[i] >> 7) & 0xFF;
    votes += (e >= 108 && e <= 131) ? 1 : 0;
  }
  return votes >= 32;
}

// ---- full barrier (fenced release/acquire; phase transitions only) ---------
__device__ __forceinline__ void gbar(unsigned* ctrs, unsigned gen) {
  __syncthreads();
  if (threadIdx.x == 0) {
    __hip_atomic_fetch_add(&ctrs[(blockIdx.x & 31) * 32], 1u,
                           __ATOMIC_RELEASE, __HIP_MEMORY_SCOPE_AGENT);
  }
  if (threadIdx.x < 32) {
    while (__hip_atomic_load(&ctrs[threadIdx.x * 32], __ATOMIC_RELAXED,
                             __HIP_MEMORY_SCOPE_AGENT) < gen * 8u) {
      __builtin_amdgcn_s_sleep(1);
    }
    (void)__hip_atomic_load(&ctrs[threadIdx.x * 32], __ATOMIC_ACQUIRE,
                            __HIP_MEMORY_SCOPE_AGENT);
  }
  __syncthreads();
}

// 8-elem chunk of a weight row (bf16 or fp32 global) -> packed fp16 uint4
__device__ __forceinline__ uint4 ldw8(const void* src, size_t off, int bf) {
  union { __half h[8]; uint4 u; } r;
  if (bf) {
    const unsigned short* s = (const unsigned short*)src + off;
    ushort4 a = *reinterpret_cast<const ushort4*>(s);
    ushort4 b = *reinterpret_cast<const ushort4*>(s + 4);
    r.h[0] = __float2half(bf2f(a.x)); r.h[1] = __float2half(bf2f(a.y));
    r.h[2] = __float2half(bf2f(a.z)); r.h[3] = __float2half(bf2f(a.w));
    r.h[4] = __float2half(bf2f(b.x)); r.h[5] = __float2half(bf2f(b.y));
    r.h[6] = __float2half(bf2f(b.z)); r.h[7] = __float2half(bf2f(b.w));
  } else {
    const float* s = (const float*)src + off;
    float4 a = *reinterpret_cast<const float4*>(s);
    float4 b = *reinterpret_cast<const float4*>(s + 4);
    r.h[0] = __float2half(a.x); r.h[1] = __float2half(a.y);
    r.h[2] = __float2half(a.z); r.h[3] = __float2half(a.w);
    r.h[4] = __float2half(b.x); r.h[5] = __float2half(b.y);
    r.h[6] = __float2half(b.z); r.h[7] = __float2half(b.w);
  }
  return r.u;
}

// ---- R-phase helpers (proven; unchanged) -----------------------------------
__device__ __forceinline__ void stage_u128(unsigned* AH, const unsigned* src,
                                           int ustr, int uoff) {
  const int t = threadIdx.x;
#pragma unroll
  for (int i = 0; i < 4; ++i) {
    int idx = t + i * THR;
    int r = idx >> 5, c4 = (idx & 31) << 2;
    uint4 v = *reinterpret_cast<const uint4*>(src + (size_t)r * ustr + uoff + c4);
    *reinterpret_cast<uint4*>(AH + r * U0S + c4) = v;
  }
}
__device__ __forceinline__ void load_w16_rows(uint4 (&wr)[2][4], const void* src,
                                              int rowbase, int bf) {
  const int t = threadIdx.x, kc = t >> 6, rt = t & 3;
#pragma unroll
  for (int j = 0; j < 2; ++j) {
    size_t rb = (size_t)(rowbase + rt * 2 + j) * 256 + kc * 32;
#pragma unroll
    for (int d = 0; d < 4; ++d) wr[j][d] = ldw8(src, rb + d * 8, bf);
  }
}
__device__ __forceinline__ void dot2_t4(float4* acc, const unsigned* A,
                                        const uint4 (&wr)[2][4]) {
  const int t = threadIdx.x;
  const int kc = t >> 6, bt = (t & 63) >> 2;
#pragma unroll
  for (int d = 0; d < 4; ++d) {
    const int k = kc * 16 + d * 4;
    uint4 h0 = *reinterpret_cast<const uint4*>(A + (bt +  0) * U0S + k);
    uint4 h1 = *reinterpret_cast<const uint4*>(A + (bt + 16) * U0S + k);
    uint4 h2 = *reinterpret_cast<const uint4*>(A + (bt + 32) * U0S + k);
    uint4 h3 = *reinterpret_cast<const uint4*>(A + (bt + 48) * U0S + k);
    dot2acc(acc[0], h0, wr[0][d]); dot2acc(acc[1], h0, wr[1][d]);
    dot2acc(acc[2], h1, wr[0][d]); dot2acc(acc[3], h1, wr[1][d]);
    dot2acc(acc[4], h2, wr[0][d]); dot2acc(acc[5], h2, wr[1][d]);
    dot2acc(acc[6], h3, wr[0][d]); dot2acc(acc[7], h3, wr[1][d]);
  }
}
__device__ __forceinline__ void reduce_R(const float4* acc, float* part, float* dst,
                                         const void* bsrc, int rowbase, int bf) {
  const int t = threadIdx.x;
  const int kc = t >> 6, tile = t & 63;
#pragma unroll
  for (int e = 0; e < 8; ++e) {
    const float4 a = acc[e];
    part[e * 512 + kc * 64 + tile] = (a.x + a.y) + (a.z + a.w);
  }
  __syncthreads();
  {
    const int r = t >> 6, b = t & 63;
    const int tl = (b & 15) * 4 + (r >> 1);
    const float* pp = part + ((b >> 4) * 2 + (r & 1)) * 512 + tl;
    float v = ((pp[0] + pp[64]) + (pp[128] + pp[192])) +
              ((pp[256] + pp[320]) + (pp[384] + pp[448]));
    dst[(size_t)b * 1024 + rowbase + r] = v + ldin(bsrc, rowbase + r, bf);
  }
  __syncthreads();
}

// ---------------------------------------------------------------------------
__global__ void __launch_bounds__(THR, 2)
__attribute__((amdgpu_waves_per_eu(2, 2)))
seq2seq_kernel(SeqParams p) {
  // smem (148736 B):
  //  [0,131072)       FRAG: A-fragments of gate-3 tiles (hf=0,1) per wave
  //                   (uint4[(wv*16 + hf*8 + kc)*64 + lane])  [E0/E1]
  //                   aliases: producer YW | R: AH0+part | dec: R0L..ZV
  //  [131072,135168)  GF fp32[1024]  (decoder only now)
  //  [135168,139264)  PREB fp32[1024]
  //  [139264,143360)  E0: PREWf fp32[1024];  E1: GWL uint[2][512]
  //  [143360,147456)  XROW fp32[1024]    (E0)
  //  [147456,148480)  H16 uint[256]  (double-buffered packed h)
  //  [148480,148736)  YL
  __shared__ __align__(16) char smem[148736];
  uint4* FRAGu4 = (uint4*)smem;
  float* GF     = (float*)(smem + 131072);
  float* PREB   = (float*)(smem + 135168);
  float* PREWf  = (float*)(smem + 139264);
  unsigned* GWL = (unsigned*)(smem + 139264);
  float* XROW   = (float*)(smem + 143360);
  unsigned* H16 = (unsigned*)(smem + 147456);
  float* YL     = (float*)(smem + 148480);

  const int w = blockIdx.x;
  const int t = threadIdx.x;
  float* ws = p.ws;
  unsigned* ctrs = p.ctrs;
  unsigned* y0w   = (unsigned*)(ws + Y0OF);
  unsigned* EHL1u = (unsigned*)(ws + EHL1);
  uint4* WIH1Tu4  = (uint4*)(ws + WIH1T);
  unsigned* GWu   = (unsigned*)(ws + GWR);
  unsigned* flg   = (unsigned*)(ws + PCF);
  uint4* DWu4     = (uint4*)(ws + Y0OF);   // decoder transposed dWih1 (after R)
  unsigned genF = 0;
  const int bfm = detect_bf16(p.x);
  const int enc_act = (w < 128);
  const int d = (w >> 6) & 1, b = w & 63;
  const int wv = t >> 6, l = t & 63;       // wave, lane
  const int lg = l >> 4, lr = l & 15;      // k-group, row-in-tile

  uint4 awr[6][8];   // resident A-tiles: (g,hf) g=0..2, hf=0..1; idx g*2+hf

  // ============================ E0 prep ====================================
  {
    if (w == 0) {                         // reset producer/consumer flags
      for (int i = t; i < 8192; i += THR) flg[i] = 0u;
    }
    if (enc_act) {
      const void* whh0 = bfm ? (const void*)((const unsigned short*)p.eWhh0 + (size_t)d * 262144)
                             : (const void*)((const float*)p.eWhh0 + (size_t)d * 262144);
#pragma unroll
      for (int g = 0; g < 3; ++g)
#pragma unroll
        for (int hf = 0; hf < 2; ++hf)
#pragma unroll
          for (int kc = 0; kc < 8; ++kc)
            awr[g * 2 + hf][kc] = ldw8(whh0,
                (size_t)(g * 256 + wv * 32 + hf * 16 + lr) * 256 + kc * 32 + lg * 8, bfm);
#pragma unroll
      for (int hf = 0; hf < 2; ++hf)      // gate-3 tiles -> FRAG LDS
#pragma unroll
        for (int kc = 0; kc < 8; ++kc)
          FRAGu4[(wv * 16 + hf * 8 + kc) * 64 + l] = ldw8(whh0,
              (size_t)(768 + wv * 32 + hf * 16 + lr) * 256 + kc * 32 + lg * 8, bfm);
#pragma unroll
      for (int q = 0; q < 2; ++q) {
        PREB[t + q * 512]  = ldin(p.eB0,   d * 1024 + t + q * 512, bfm);
        PREWf[t + q * 512] = ldin(p.eWih0, d * 1024 + t + q * 512, bfm);
        XROW[t + q * 512]  = ldin(p.x, (size_t)b * 1024 + t + q * 512, bfm);
      }
      if (t < 256) H16[t] = 0u;           // both h buffers
    } else {
      // idle WGs pre-transpose Wih1 during E0 (consumed by producers in E1)
#pragma unroll
      for (int q = 0; q < 2; ++q) {
        int idx = (w - 128) * 1024 + q * 512 + t;   // 131072 uint4 total
        int dd = idx >> 16, rem = idx & 65535;
        int kc = rem >> 10, row = rem & 1023;
        WIH1Tu4[idx] = ldw8(p.eWih1, (size_t)dd * 524288 + (size_t)row * 512 + kc * 8, bfm);
      }
    }
  }
  gbar(ctrs, ++genF);

  // ======= E0: 1024 steps, MFMA dot + in-lane cell, ONE sync, 0 gld ========
  if (enc_act) {
    float cc[2][4];
#pragma unroll
    for (int hf = 0; hf < 2; ++hf)
#pragma unroll
      for (int r = 0; r < 4; ++r) cc[hf][r] = 0.f;
    int pp = 0;
    uint2 py[2]; py[0] = make_uint2(0, 0); py[1] = make_uint2(0, 0);
    int ptt = -1;
    for (int st = 0; st < 1024; ++st) {
      const int tt = d ? (1023 - st) : st;
      if (ptt >= 0 && lr == 0) {          // deferred y0 store (prev step)
#pragma unroll
        for (int hf = 0; hf < 2; ++hf)
          *reinterpret_cast<uint2*>(y0w + (size_t)ptt * 16384 + (size_t)b * 256 +
                                    d * 128 + wv * 16 + hf * 8 + lg * 2) = py[hf];
      }
      float xv = XROW[tt];
      floatx4 acc[8];
#pragma unroll
      for (int m = 0; m < 8; ++m) acc[m] = (floatx4){0.f, 0.f, 0.f, 0.f};
      const uint4* hb4 = (const uint4*)(H16 + pp * 128);
#pragma unroll
      for (int kc = 0; kc < 8; ++kc) {
        uint4 bu = hb4[kc * 4 + lg];      // h replicated across cols
        uint4 a6 = FRAGu4[(wv * 16 + kc) * 64 + l];
        uint4 a7 = FRAGu4[(wv * 16 + 8 + kc) * 64 + l];
        acc[0] = mfma16(awr[0][kc], bu, acc[0]);
        acc[1] = mfma16(awr[1][kc], bu, acc[1]);
        acc[2] = mfma16(awr[2][kc], bu, acc[2]);
        acc[3] = mfma16(awr[3][kc], bu, acc[3]);
        acc[4] = mfma16(awr[4][kc], bu, acc[4]);
        acc[5] = mfma16(awr[5][kc], bu, acc[5]);
        acc[6] = mfma16(a6, bu, acc[6]);
        acc[7] = mfma16(a7, bu, acc[7]);
      }
      // in-lane cell: 8 columns per lane (redundant across lr; no divergence)
#pragma unroll
      for (int hf = 0; hf < 2; ++hf) {
        const int c0 = wv * 32 + hf * 16 + lg * 4;
        float4 pbI = *reinterpret_cast<const float4*>(PREB + c0);
        float4 pbF = *reinterpret_cast<const float4*>(PREB + 256 + c0);
        float4 pbG = *reinterpret_cast<const float4*>(PREB + 512 + c0);
        float4 pbO = *reinterpret_cast<const float4*>(PREB + 768 + c0);
        float4 pwI = *reinterpret_cast<const float4*>(PREWf + c0);
        float4 pwF = *reinterpret_cast<const float4*>(PREWf + 256 + c0);
        float4 pwG = *reinterpret_cast<const float4*>(PREWf + 512 + c0);
        float4 pwO = *reinterpret_cast<const float4*>(PREWf + 768 + c0);
        const float* bI = &pbI.x; const float* bF = &pbF.x;
        const float* bG = &pbG.x; const float* bO = &pbO.x;
        const float* wI = &pwI.x; const float* wF = &pwF.x;
        const float* wG = &pwG.x; const float* wO = &pwO.x;
        unsigned short hu[4];
#pragma unroll
        for (int r = 0; r < 4; ++r) {
          float gi = acc[0 + hf][r] + bI[r] + xv * wI[r];
          float gf = acc[2 + hf][r] + bF[r] + xv * wF[r];
          float gg = acc[4 + hf][r] + bG[r] + xv * wG[r];
          float go = acc[6 + hf][r] + bO[r] + xv * wO[r];
          float cn = sigm(gf) * cc[hf][r] + sigm(gi) * ftanh(gg);
          float hn = sigm(go) * ftanh(cn);
          cc[hf][r] = cn;
          hu[r] = f2h_u(hn);
        }
        unsigned u0 = (unsigned)hu[0] | ((unsigned)hu[1] << 16);
        unsigned u1 = (unsigned)hu[2] | ((unsigned)hu[3] << 16);
        py[hf] = make_uint2(u0, u1);
        if (lr == 0) {
          *reinterpret_cast<uint2*>(H16 + (pp ^ 1) * 128 + wv * 16 + hf * 8 + lg * 2) =
              make_uint2(u0, u1);
          if (st == 1023) {
            float4 cv; cv.x = cc[hf][0]; cv.y = cc[hf][1];
            cv.z = cc[hf][2]; cv.w = cc[hf][3];
            *reinterpret_cast<float4*>(ws + ECL0 + d * 16384 + b * 256 + c0) = cv;
          }
        }
      }
      ptt = tt;
      __syncthreads();
      pp ^= 1;
    }
    // tail: final y0 row (before the publishing gbar)
    if (lr == 0) {
#pragma unroll
      for (int hf = 0; hf < 2; ++hf)
        *reinterpret_cast<uint2*>(y0w + (size_t)ptt * 16384 + (size_t)b * 256 +
                                  d * 128 + wv * 16 + hf * 8 + lg * 2) = py[hf];
    }
  }
  gbar(ctrs, ++genF);   // y0 / ECL0 visible

  // ============================ E1 prep ====================================
  {
    if (enc_act) {
      const void* whh1 = bfm ? (const void*)((const unsigned short*)p.eWhh1 + (size_t)d * 262144)
                             : (const void*)((const float*)p.eWhh1 + (size_t)d * 262144);
#pragma unroll
      for (int g = 0; g < 3; ++g)
#pragma unroll
        for (int hf = 0; hf < 2; ++hf)
#pragma unroll
          for (int kc = 0; kc < 8; ++kc)
            awr[g * 2 + hf][kc] = ldw8(whh1,
                (size_t)(g * 256 + wv * 32 + hf * 16 + lr) * 256 + kc * 32 + lg * 8, bfm);
#pragma unroll
      for (int hf = 0; hf < 2; ++hf)
#pragma unroll
        for (int kc = 0; kc < 8; ++kc)
          FRAGu4[(wv * 16 + hf * 8 + kc) * 64 + l] = ldw8(whh1,
              (size_t)(768 + wv * 32 + hf * 16 + lr) * 256 + kc * 32 + lg * 8, bfm);
#pragma unroll
      for (int q = 0; q < 2; ++q)
        PREB[t + q * 512] = ldin(p.eB1, d * 1024 + t + q * 512, bfm);
      if (t < 256) H16[t] = 0u;
    }
  }
  gbar(ctrs, ++genF);   // W' + y0 + flags visible

  // ====================== E1: consumers + producers ========================
  if (enc_act) {
    float cc[2][4];
#pragma unroll
    for (int hf = 0; hf < 2; ++hf)
#pragma unroll
      for (int r = 0; r < 4; ++r) cc[hf][r] = 0.f;
    int pp = 0, sel = 0;
    // prologue: wait window 0, stage GW step 0 into GWL[0]
    if (t == 0) {
      while (__hip_atomic_load(&flg[w * 64], __ATOMIC_RELAXED,
                               __HIP_MEMORY_SCOPE_AGENT) < 1u) {
        __builtin_amdgcn_s_sleep(1);
      }
    }
    __atomic_signal_fence(__ATOMIC_ACQUIRE);
    __syncthreads();
    GWL[t] = __hip_atomic_load(&GWu[(unsigned)w * 8192 + t],
                               __ATOMIC_RELAXED, __HIP_MEMORY_SCOPE_AGENT);
    __syncthreads();
    for (int st = 0; st < 1024; ++st) {
      const int win = st >> 3, sl = st & 7;
      // stage GW for step st+1 into GWL[sel^1] (one step ahead)
      if (st < 1023) {
        const int su = st + 1, wn = su >> 3;
        if ((su & 7) == 0) {
          if (t == 0) {
            while (__hip_atomic_load(&flg[w * 64], __ATOMIC_RELAXED,
                                     __HIP_MEMORY_SCOPE_AGENT) < (unsigned)(wn + 1)) {
              __builtin_amdgcn_s_sleep(1);
            }
          }
          __atomic_signal_fence(__ATOMIC_ACQUIRE);
          __syncthreads();
        }
        GWL[(sel ^ 1) * 512 + t] = __hip_atomic_load(
            &GWu[(unsigned)w * 8192 + (unsigned)(wn & 1) * 4096 +
                 (unsigned)(su & 7) * 512 + t],
            __ATOMIC_RELAXED, __HIP_MEMORY_SCOPE_AGENT);
      }
      floatx4 acc[8];
#pragma unroll
      for (int m = 0; m < 8; ++m) acc[m] = (floatx4){0.f, 0.f, 0.f, 0.f};
      const uint4* hb4 = (const uint4*)(H16 + pp * 128);
#pragma unroll
      for (int kc = 0; kc < 8; ++kc) {
        uint4 bu = hb4[kc * 4 + lg];
        uint4 a6 = FRAGu4[(wv * 16 + kc) * 64 + l];
        uint4 a7 = FRAGu4[(wv * 16 + 8 + kc) * 64 + l];
        acc[0] = mfma16(awr[0][kc], bu, acc[0]);
        acc[1] = mfma16(awr[1][kc], bu, acc[1]);
        acc[2] = mfma16(awr[2][kc], bu, acc[2]);
        acc[3] = mfma16(awr[3][kc], bu, acc[3]);
        acc[4] = mfma16(awr[4][kc], bu, acc[4]);
        acc[5] = mfma16(awr[5][kc], bu, acc[5]);
        acc[6] = mfma16(a6, bu, acc[6]);
        acc[7] = mfma16(a7, bu, acc[7]);
      }
      // in-lane cell; GW term from GWL[sel] (staged last step)
#pragma unroll
      for (int hf = 0; hf < 2; ++hf) {
        const int c0 = wv * 32 + hf * 16 + lg * 4;
        float4 pbI = *reinterpret_cast<const float4*>(PREB + c0);
        float4 pbF = *reinterpret_cast<const float4*>(PREB + 256 + c0);
        float4 pbG = *reinterpret_cast<const float4*>(PREB + 512 + c0);
        float4 pbO = *reinterpret_cast<const float4*>(PREB + 768 + c0);
        uint4 gA = *reinterpret_cast<const uint4*>(GWL + sel * 512 + c0);
        uint4 gB = *reinterpret_cast<const uint4*>(GWL + sel * 512 + 256 + c0);
        const float* bI = &pbI.x; const float* bF = &pbF.x;
        const float* bG = &pbG.x; const float* bO = &pbO.x;
        const unsigned* ga = &gA.x; const unsigned* gbp = &gB.x;
        unsigned short hu[4];
#pragma unroll
        for (int r = 0; r < 4; ++r) {
          float gi = acc[0 + hf][r] + bI[r] + hf2f((unsigned short)(ga[r] & 0xffffu));
          float gf = acc[2 + hf][r] + bF[r] + hf2f((unsigned short)(gbp[r] & 0xffffu));
          float gg = acc[4 + hf][r] + bG[r] + hf2f((unsigned short)(ga[r] >> 16));
          float go = acc[6 + hf][r] + bO[r] + hf2f((unsigned short)(gbp[r] >> 16));
          float cn = sigm(gf) * cc[hf][r] + sigm(gi) * ftanh(gg);
          float hn = sigm(go) * ftanh(cn);
          cc[hf][r] = cn;
          hu[r] = f2h_u(hn);
        }
        unsigned u0 = (unsigned)hu[0] | ((unsigned)hu[1] << 16);
        unsigned u1 = (unsigned)hu[2] | ((unsigned)hu[3] << 16);
        if (lr == 0) {
          *reinterpret_cast<uint2*>(H16 + (pp ^ 1) * 128 + wv * 16 + hf * 8 + lg * 2) =
              make_uint2(u0, u1);
          if (st == 1023) {
            *reinterpret_cast<uint2*>(EHL1u + d * 8192 + b * 128 + wv * 16 + hf * 8 + lg * 2) =
                make_uint2(u0, u1);
            float4 cv; cv.x = cc[hf][0]; cv.y = cc[hf][1];
            cv.z = cc[hf][2]; cv.w = cc[hf][3];
            *reinterpret_cast<float4*>(ws + ECL1 + d * 16384 + b * 256 + c0) = cv;
          }
        }
      }
      __syncthreads();
      if (sl == 7 && t == 0)
        __hip_atomic_store(&flg[w * 64 + 32], (unsigned)(win + 1),
                           __ATOMIC_RELAXED, __HIP_MEMORY_SCOPE_AGENT);
      pp ^= 1; sel ^= 1;
    }
  } else {
    // -------- producer: GW = y0 @ Wih1^T, window-by-window -----------------
    const int chain = w - 128, dp = chain >> 6, bp = chain & 63;
    const uint4* Wt = WIH1Tu4 + (size_t)dp * 65536;
    uint4* YWu4 = (uint4*)smem;          // [8][64] uint4 (FRAG unused here)
    for (int win = 0; win < 128; ++win) {
      if (win >= 2) {
        if (t == 0) {
          while (__hip_atomic_load(&flg[chain * 64 + 32], __ATOMIC_RELAXED,
                                   __HIP_MEMORY_SCOPE_AGENT) < (unsigned)(win - 1)) {
            __builtin_amdgcn_s_sleep(1);
          }
        }
        __syncthreads();
      }
      {
        int s = t >> 6, kcc = t & 63;
        int tw = dp ? (1023 - (win * 8 + s)) : (win * 8 + s);
        YWu4[s * 64 + kcc] =
            *(const uint4*)(y0w + (size_t)tw * 16384 + (size_t)bp * 256 + kcc * 4);
      }
      __syncthreads();
      float a0[8], a1[8];
#pragma unroll
      for (int s = 0; s < 8; ++s) { a0[s] = 0.f; a1[s] = 0.f; }
      for (int kc = 0; kc < 64; ++kc) {
        uint4 w0 = Wt[kc * 1024 + t];
        uint4 w1 = Wt[kc * 1024 + 512 + t];
#pragma unroll
        for (int s = 0; s < 8; ++s) {
          uint4 yv = YWu4[s * 64 + kc];
          a0[s] = dot1(a0[s], yv, w0);
          a1[s] = dot1(a1[s], yv, w1);
        }
      }
      const unsigned gb = (unsigned)chain * 8192 + (unsigned)(win & 1) * 4096;
#pragma unroll
      for (int s = 0; s < 8; ++s) {
        unsigned pw = (unsigned)f2h_u(a0[s]) | ((unsigned)f2h_u(a1[s]) << 16);
        __hip_atomic_store(&GWu[gb + s * 512 + t], pw,
                           __ATOMIC_RELAXED, __HIP_MEMORY_SCOPE_AGENT);
      }
      __syncthreads();                   // drains vmcnt: sc1 stores at IC
      if (t == 0)
        __hip_atomic_store(&flg[chain * 64], (unsigned)(win + 1),
                           __ATOMIC_RELAXED, __HIP_MEMORY_SCOPE_AGENT);
    }
  }
  gbar(ctrs, ++genF);   // EHL1/ECL1 visible

  // ===================== decoder recurrent consts R ========================
  {
    unsigned* AH0 = (unsigned*)smem;
    float* part = (float*)(smem + 33792);
    const int m = w >> 6, wl6 = w & 63;
    const void* whh;
    if (bfm) whh = (m < 2) ? (const void*)((const unsigned short*)p.dWhh0 + (size_t)m * 262144)
                           : (const void*)((const unsigned short*)p.dWhh1 + (size_t)(m - 2) * 262144);
    else     whh = (m < 2) ? (const void*)((const float*)p.dWhh0 + (size_t)m * 262144)
                           : (const void*)((const float*)p.dWhh1 + (size_t)(m - 2) * 262144);
    const void* bb;
    if (bfm) bb = (m < 2) ? (const void*)((const unsigned short*)p.dB0 + m * 1024)
                          : (const void*)((const unsigned short*)p.dB1 + (m - 2) * 1024);
    else     bb = (m < 2) ? (const void*)((const float*)p.dB0 + m * 1024)
                          : (const void*)((const float*)p.dB1 + (m - 2) * 1024);
    if (m == 0)      stage_u128(AH0, y0w + (size_t)1023 * 16384, 256, 0);
    else if (m == 1) stage_u128(AH0, y0w, 256, 128);
    else             stage_u128(AH0, EHL1u + (m - 2) * 8192, 128, 0);
    __syncthreads();
    float* dst = ws + ROF + m * 65536;
    for (int pass = 0; pass < 2; ++pass) {
      const int rowbase = wl6 * 16 + pass * 8;
      uint4 wrA[2][4];
      load_w16_rows(wrA, whh, rowbase, bfm);
      float4 acc[8];
#pragma unroll
      for (int e = 0; e < 8; ++e) acc[e] = make_float4(0.f, 0.f, 0.f, 0.f);
      dot2_t4(acc, AH0, wrA);
      reduce_R(acc, part, dst, bb, rowbase, bfm);
    }
  }
  gbar(ctrs, ++genF);   // ROF visible

  // ============================ decoder prep ===============================
  {
    int idx = w * 512 + t;               // transposed fp16 dWih1 (dead y0 head)
    int dd = idx >> 16, rem = idx & 65535;
    int kc = rem >> 10, row = rem & 1023;
    DWu4[idx] = ldw8(p.dWih1, (size_t)dd * 524288 + (size_t)row * 512 + kc * 8, bfm);
  }
  float r1i = 0.f, r1f = 0.f, r1g = 0.f, r1o = 0.f, coldc = 0.f, fwc = 0.f, fcb = 0.f;
  {
    float* R0L  = (float*)smem;          // [2][1024]
    float* WI0L = (float*)(smem + 8192); // [2][1024]
    float* C0L  = (float*)(smem + 16384);// [2][256]
    if (w < 64) {
      const int bq = w;
#pragma unroll
      for (int i = 0; i < 4; ++i) {
        int r = t + i * THR;
        int dz = r >> 10, rr = r & 1023;
        R0L[r]  = ws[ROF + dz * 65536 + (size_t)bq * 1024 + rr];
        WI0L[r] = ldin(p.dWih0, dz * 1024 + rr, bfm);
      }
      C0L[t >= 512 ? 0 : t] = ws[ECL0 + (t >> 8) * 16384 + (size_t)bq * 256 + (t & 255)];
      const int dd2 = t >> 8, col = t & 255;
      r1i = ws[ROF + (2 + dd2) * 65536 + (size_t)bq * 1024 +       col];
      r1f = ws[ROF + (2 + dd2) * 65536 + (size_t)bq * 1024 + 256 + col];
      r1g = ws[ROF + (2 + dd2) * 65536 + (size_t)bq * 1024 + 512 + col];
      r1o = ws[ROF + (2 + dd2) * 65536 + (size_t)bq * 1024 + 768 + col];
      coldc = ws[ECL1 + dd2 * 16384 + (size_t)bq * 256 + col];
      fwc = ldin(p.fcW, dd2 * 256 + col, bfm);
      fcb = ldin(p.fcb, 0, bfm);
    }
  }
  gbar(ctrs, ++genF);   // DW' visible

  // ===================== decoder loop: one WG per batch ====================
  if (w < 64) {
    const int bq = w;
    float* R0L  = (float*)smem;
    float* WI0L = (float*)(smem + 8192);
    float* C0L  = (float*)(smem + 16384);
    unsigned* ZV = (unsigned*)(smem + 18432);
    const int dd2 = t >> 8, col = t & 255;
    const uint4* DWt = DWu4 + (size_t)dd2 * 65536;

    {
      float gi = R0L[dd2 * 1024 +       col];
      float gf = R0L[dd2 * 1024 + 256 + col];
      float gg = R0L[dd2 * 1024 + 512 + col];
      float go = R0L[dd2 * 1024 + 768 + col];
      float cold = C0L[dd2 * 256 + col];
      float cn = sigm(gf) * cold + sigm(gi) * ftanh(gg);
      float hz = sigm(go) * ftanh(cn);
      ((unsigned short*)ZV)[t] = f2h_u(hz);
    }
    __syncthreads();

    float yp1 = 3.0e38f, yp2 = -3.0e38f;
    for (int st = 0; st < 1024; ++st) {
      float ai = 0.f, af = 0.f, ag = 0.f, ao = 0.f;
      for (int kc = 0; kc < 64; ++kc) {
        uint4 zv = *(const uint4*)(ZV + kc * 4);
        uint4 w0 = DWt[kc * 1024 +       col];
        uint4 w1 = DWt[kc * 1024 + 256 + col];
        uint4 w2 = DWt[kc * 1024 + 512 + col];
        uint4 w3 = DWt[kc * 1024 + 768 + col];
        ai = dot1(ai, zv, w0);
        af = dot1(af, zv, w1);
        ag = dot1(ag, zv, w2);
        ao = dot1(ao, zv, w3);
      }
      float gi = ai + r1i, gf = af + r1f, gg = ag + r1g, go = ao + r1o;
      float cn = sigm(gf) * coldc + sigm(gi) * ftanh(gg);
      float h1 = sigm(go) * ftanh(cn);
      GF[t] = h1 * fwc;
      __syncthreads();
      if (t < 64) {
        const float* q = GF + t;
        GF[t] = ((q[0] + q[64]) + (q[128] + q[192])) +
                ((q[256] + q[320]) + (q[384] + q[448]));
      }
      __syncthreads();
      if (t == 0) {
        float yy = fcb;
        for (int i = 0; i < 64; ++i) yy += GF[i];
        YL[0] = yy;
      }
      __syncthreads();
      float ynew = YL[0];
      if (t == 0) stout(p.out, (size_t)bq * 1024 + st, ynew, bfm);
      if (ynew == yp1) {
        for (int t2 = st + 1 + t; t2 < 1024; t2 += THR)
          stout(p.out, (size_t)bq * 1024 + t2, ynew, bfm);
        break;
      }
      if (ynew == yp2) {
        for (int t2 = st + 1 + t; t2 < 1024; t2 += THR)
          stout(p.out, (size_t)bq * 1024 + t2, ((t2 - st) & 1) ? yp1 : ynew, bfm);
        break;
      }
      yp2 = yp1; yp1 = ynew;
      if (st < 1023) {
        __syncthreads();
        float gi2 = ynew * WI0L[dd2 * 1024 +       col] + R0L[dd2 * 1024 +       col];
        float gf2 = ynew * WI0L[dd2 * 1024 + 256 + col] + R0L[dd2 * 1024 + 256 + col];
        float gg2 = ynew * WI0L[dd2 * 1024 + 512 + col] + R0L[dd2 * 1024 + 512 + col];
        float go2 = ynew * WI0L[dd2 * 1024 + 768 + col] + R0L[dd2 * 1024 + 768 + col];
        float cold = C0L[dd2 * 256 + col];
        float cn2 = sigm(gf2) * cold + sigm(gi2) * ftanh(gg2);
        float hz = sigm(go2) * ftanh(cn2);
        ((unsigned short*)ZV)[t] = f2h_u(hz);
        __syncthreads();
      }
    }
  }
}

// diagnostic: if ws too small, encode ws_size (MB) into the output signature
__global__ void fill_sig(unsigned short* out, int n, float val) {
  int i = blockIdx.x * 256 + threadIdx.x;
  __hip_bfloat16 b = __float2bfloat16(val);
  if (i < n) out[i] = *reinterpret_cast<unsigned short*>(&b);
}

extern "C" void kernel_launch(void* const* d_in, const int* in_sizes, int n_in,
                              void* d_out, int out_size, void* d_ws, size_t ws_size,
                              hipStream_t stream) {
  (void)in_sizes; (void)n_in;
  if (ws_size < WS_REQ_BYTES) {
    float sig = 2048.0f + (float)(ws_size >> 20);
    fill_sig<<<(out_size + 255) / 256, 256, 0, stream>>>(
        (unsigned short*)d_out, out_size, sig);
    return;
  }
  hipMemsetAsync(d_ws, 0, 8192, stream);  // zero barrier counters

  SeqParams p;
  p.x     = d_in[0];
  p.eWih0 = d_in[1];
  p.eWhh0 = d_in[2];
  p.eB0   = d_in[3];
  p.eWih1 = d_in[4];
  p.eWhh1 = d_in[5];
  p.eB1   = d_in[6];
  p.dWih0 = d_in[7];
  p.dWhh0 = d_in[8];
  p.dB0   = d_in[9];
  p.dWih1 = d_in[10];
  p.dWhh1 = d_in[11];
  p.dB1   = d_in[12];
  p.fcW   = d_in[13];
  p.fcb   = d_in[14];
  p.out   = d_out;
  p.ws    = (float*)d_ws;
  p.ctrs  = (unsigned*)d_ws;

  seq2seq_kernel<<<dim3(NWG), dim3(THR), 0, stream>>>(p);
}

// Round 12
// 5865.215 us; speedup vs baseline: 1.4512x; 1.4512x over previous
//
#include <hip/hip_runtime.h>
#include <hip/hip_bf16.h>
#include <hip/hip_fp16.h>
#include <math.h>

// ---------------------------------------------------------------------------
// Seq2Seq (bi-LSTM encoder x2 + fixed-state decoder), B=64 T=1024 H=256.
// Round 12 = REVERT to round 9 (best verified: 5894 us).
// Post-mortem of rounds 10/11 (MFMA ports): dot engine choice and barrier
// count both proven non-critical; the ~2.4 us/step floor is the serial
// {h-publish -> barrier -> broadcast -> dot -> cell} chain at 2 waves/SIMD.
// Round 9 structure: VALU fdot2 dot, fused-pair cell, ONE barrier/step,
// deferred y0 store, all weights resident (regs 3/4 + swizzled LDS 1/4),
// E1 input GEMM on producer WGs, fast transcendentals.
// ---------------------------------------------------------------------------

#define NWG 256
#define THR 512
#define U0S 132      // R-phase A-tile stride in uints

// ws layout (float offsets); first 2048 floats = barrier counters (8 KB)
#define ECL0   2048                 // enc l0 final c (fp32): [dir*16384 + b*256 + k]
#define EHL1   (ECL0 + 32768)       // enc l1 final h packed fp16: uint[dir*8192 + b*128 + p]
#define ECL1   (EHL1 + 16384)       // enc l1 final c (fp32)
#define ROF    (ECL1 + 32768)       // decoder R consts (fp32): [m*65536 + b*1024 + r]
#define WIH1T  (ROF + 262144)       // transposed fp16 eWih1: uint4[dir*65536 + kc*1024 + row]
#define GWR    (WIH1T + 524288)     // GW ring: uint[chain*8192 + slot*4096 + s*512 + g]
#define PCF    (GWR + 1048576)      // flags: uint[chain*64]=produced, [chain*64+32]=consumed
#define Y0OF   (PCF + 8192)         // packed fp16 y0: uint[t*16384 + b*256 + dir*128 + p]
#define WS_REQ_BYTES ((size_t)(Y0OF + 16777216) * 4)   // ~71.4 MB (unchanged)

struct SeqParams {
  const void *x, *eWih0, *eWhh0, *eB0, *eWih1, *eWhh1, *eB1;
  const void *dWih0, *dWhh0, *dB0, *dWih1, *dWhh1, *dB1, *fcW, *fcb;
  void* out;
  float* ws;
  unsigned* ctrs;
};

typedef _Float16 hlf2 __attribute__((ext_vector_type(2)));

__device__ __forceinline__ float bf2f(unsigned short u) {
  return __uint_as_float(((unsigned)u) << 16);
}
__device__ __forceinline__ float hf2f(unsigned short u) {
  __half_raw r; r.x = u; return __half2float(__half(r));
}
__device__ __forceinline__ unsigned short f2h_u(float f) {
  __half h = __float2half(f);
  return *reinterpret_cast<unsigned short*>(&h);
}

// ---- fast branch-free transcendentals --------------------------------------
__device__ __forceinline__ float fexp2(float x) {
#if __has_builtin(__builtin_amdgcn_exp2f)
  return __builtin_amdgcn_exp2f(x);
#else
  return exp2f(x);
#endif
}
__device__ __forceinline__ float frcp(float x) {
#if __has_builtin(__builtin_amdgcn_rcpf)
  return __builtin_amdgcn_rcpf(x);
#else
  return 1.0f / x;
#endif
}
__device__ __forceinline__ float sigm(float v) {
  return frcp(1.0f + fexp2(v * -1.44269504f));
}
__device__ __forceinline__ float ftanh(float v) {
  return fmaf(-2.0f, frcp(1.0f + fexp2(v * 2.88539008f)), 1.0f);
}

#if __has_builtin(__builtin_amdgcn_fdot2)
__device__ __forceinline__ float fdot2(hlf2 a, hlf2 b, float c) {
  return __builtin_amdgcn_fdot2(a, b, c, false);
}
#else
__device__ __forceinline__ float fdot2(hlf2 a, hlf2 b, float c) {
  return c + (float)a[0] * (float)b[0] + (float)a[1] * (float)b[1];
}
#endif

__device__ __forceinline__ float dot1(float a, const uint4& x, const uint4& y) {
  const hlf2* xp = reinterpret_cast<const hlf2*>(&x);
  const hlf2* yp = reinterpret_cast<const hlf2*>(&y);
  a = fdot2(xp[0], yp[0], a);
  a = fdot2(xp[1], yp[1], a);
  a = fdot2(xp[2], yp[2], a);
  a = fdot2(xp[3], yp[3], a);
  return a;
}
__device__ __forceinline__ void dot2acc(float4& a, const uint4& hv, const uint4& wv) {
  const hlf2* hp = reinterpret_cast<const hlf2*>(&hv);
  const hlf2* wp = reinterpret_cast<const hlf2*>(&wv);
  a.x = fdot2(hp[0], wp[0], a.x);
  a.y = fdot2(hp[1], wp[1], a.y);
  a.z = fdot2(hp[2], wp[2], a.z);
  a.w = fdot2(hp[3], wp[3], a.w);
}

__device__ __forceinline__ float ldin(const void* p_, size_t i, int bf) {
  return bf ? bf2f(((const unsigned short*)p_)[i]) : ((const float*)p_)[i];
}
__device__ __forceinline__ void stout(void* o, size_t i, float v, int bf) {
  if (bf) ((__hip_bfloat16*)o)[i] = __float2bfloat16(v);
  else    ((float*)o)[i] = v;
}

__device__ __forceinline__ int detect_bf16(const void* xp) {
  const unsigned* u = (const unsigned*)xp;
  int votes = 0;
#pragma unroll 8
  for (int i = 0; i < 64; ++i) {
    unsigned e = (u[i] >> 7) & 0xFF;
    votes += (e >= 108 && e <= 131) ? 1 : 0;
  }
  return votes >= 32;
}

// ---- full barrier (fenced release/acquire; phase transitions only) ---------
__device__ __forceinline__ void gbar(unsigned* ctrs, unsigned gen) {
  __syncthreads();
  if (threadIdx.x == 0) {
    __hip_atomic_fetch_add(&ctrs[(blockIdx.x & 31) * 32], 1u,
                           __ATOMIC_RELEASE, __HIP_MEMORY_SCOPE_AGENT);
  }
  if (threadIdx.x < 32) {
    while (__hip_atomic_load(&ctrs[threadIdx.x * 32], __ATOMIC_RELAXED,
                             __HIP_MEMORY_SCOPE_AGENT) < gen * 8u) {
      __builtin_amdgcn_s_sleep(1);
    }
    (void)__hip_atomic_load(&ctrs[threadIdx.x * 32], __ATOMIC_ACQUIRE,
                            __HIP_MEMORY_SCOPE_AGENT);
  }
  __syncthreads();
}

// 8-elem chunk of a weight row (bf16 or fp32 global) -> packed fp16 uint4
__device__ __forceinline__ uint4 ldw8(const void* src, size_t off, int bf) {
  union { __half h[8]; uint4 u; } r;
  if (bf) {
    const unsigned short* s = (const unsigned short*)src + off;
    ushort4 a = *reinterpret_cast<const ushort4*>(s);
    ushort4 b = *reinterpret_cast<const ushort4*>(s + 4);
    r.h[0] = __float2half(bf2f(a.x)); r.h[1] = __float2half(bf2f(a.y));
    r.h[2] = __float2half(bf2f(a.z)); r.h[3] = __float2half(bf2f(a.w));
    r.h[4] = __float2half(bf2f(b.x)); r.h[5] = __float2half(bf2f(b.y));
    r.h[6] = __float2half(bf2f(b.z)); r.h[7] = __float2half(bf2f(b.w));
  } else {
    const float* s = (const float*)src + off;
    float4 a = *reinterpret_cast<const float4*>(s);
    float4 b = *reinterpret_cast<const float4*>(s + 4);
    r.h[0] = __float2half(a.x); r.h[1] = __float2half(a.y);
    r.h[2] = __float2half(a.z); r.h[3] = __float2half(a.w);
    r.h[4] = __float2half(b.x); r.h[5] = __float2half(b.y);
    r.h[6] = __float2half(b.z); r.h[7] = __float2half(b.w);
  }
  return r.u;
}

// ---- R-phase helpers (proven; unchanged) -----------------------------------
__device__ __forceinline__ void stage_u128(unsigned* AH, const unsigned* src,
                                           int ustr, int uoff) {
  const int t = threadIdx.x;
#pragma unroll
  for (int i = 0; i < 4; ++i) {
    int idx = t + i * THR;
    int r = idx >> 5, c4 = (idx & 31) << 2;
    uint4 v = *reinterpret_cast<const uint4*>(src + (size_t)r * ustr + uoff + c4);
    *reinterpret_cast<uint4*>(AH + r * U0S + c4) = v;
  }
}
__device__ __forceinline__ void load_w16_rows(uint4 (&wr)[2][4], const void* src,
                                              int rowbase, int bf) {
  const int t = threadIdx.x, kc = t >> 6, rt = t & 3;
#pragma unroll
  for (int j = 0; j < 2; ++j) {
    size_t rb = (size_t)(rowbase + rt * 2 + j) * 256 + kc * 32;
#pragma unroll
    for (int d = 0; d < 4; ++d) wr[j][d] = ldw8(src, rb + d * 8, bf);
  }
}
__device__ __forceinline__ void dot2_t4(float4* acc, const unsigned* A,
                                        const uint4 (&wr)[2][4]) {
  const int t = threadIdx.x;
  const int kc = t >> 6, bt = (t & 63) >> 2;
#pragma unroll
  for (int d = 0; d < 4; ++d) {
    const int k = kc * 16 + d * 4;
    uint4 h0 = *reinterpret_cast<const uint4*>(A + (bt +  0) * U0S + k);
    uint4 h1 = *reinterpret_cast<const uint4*>(A + (bt + 16) * U0S + k);
    uint4 h2 = *reinterpret_cast<const uint4*>(A + (bt + 32) * U0S + k);
    uint4 h3 = *reinterpret_cast<const uint4*>(A + (bt + 48) * U0S + k);
    dot2acc(acc[0], h0, wr[0][d]); dot2acc(acc[1], h0, wr[1][d]);
    dot2acc(acc[2], h1, wr[0][d]); dot2acc(acc[3], h1, wr[1][d]);
    dot2acc(acc[4], h2, wr[0][d]); dot2acc(acc[5], h2, wr[1][d]);
    dot2acc(acc[6], h3, wr[0][d]); dot2acc(acc[7], h3, wr[1][d]);
  }
}
__device__ __forceinline__ void reduce_R(const float4* acc, float* part, float* dst,
                                         const void* bsrc, int rowbase, int bf) {
  const int t = threadIdx.x;
  const int kc = t >> 6, tile = t & 63;
#pragma unroll
  for (int e = 0; e < 8; ++e) {
    const float4 a = acc[e];
    part[e * 512 + kc * 64 + tile] = (a.x + a.y) + (a.z + a.w);
  }
  __syncthreads();
  {
    const int r = t >> 6, b = t & 63;
    const int tl = (b & 15) * 4 + (r >> 1);
    const float* pp = part + ((b >> 4) * 2 + (r & 1)) * 512 + tl;
    float v = ((pp[0] + pp[64]) + (pp[128] + pp[192])) +
              ((pp[256] + pp[320]) + (pp[384] + pp[448]));
    dst[(size_t)b * 1024 + rowbase + r] = v + ldin(bsrc, rowbase + r, bf);
  }
  __syncthreads();
}

// ---------------------------------------------------------------------------
__global__ void __launch_bounds__(THR, 2)
__attribute__((amdgpu_waves_per_eu(2, 2)))
seq2seq_kernel(SeqParams p) {
  // smem (148736 B):
  //  [0,131072)       WLDS (Whh rows 768-1023, swizzled)  [E0/E1 consumers]
  //                   aliases: producer YW | R: AH0+part | dec: R0L..ZV
  //  [131072,135168)  GF fp32[1024]  (decoder)
  //  [135168,139264)  PREB fp32[1024]
  //  [139264,143360)  PREWf fp32[1024]   (E0)
  //  [143360,147456)  XROW fp32[1024]    (E0)
  //  [147456,148480)  H16 uint[256]  (double-buffered packed h)
  //  [148480,148736)  YL
  __shared__ __align__(16) char smem[148736];
  uint4* WLDSu4 = (uint4*)smem;
  float* GF     = (float*)(smem + 131072);
  float* PREB   = (float*)(smem + 135168);
  float* PREWf  = (float*)(smem + 139264);
  float* XROW   = (float*)(smem + 143360);
  unsigned* H16 = (unsigned*)(smem + 147456);
  float* YL     = (float*)(smem + 148480);

  const int w = blockIdx.x;
  const int t = threadIdx.x;
  float* ws = p.ws;
  unsigned* ctrs = p.ctrs;
  unsigned* y0w   = (unsigned*)(ws + Y0OF);
  unsigned* EHL1u = (unsigned*)(ws + EHL1);
  uint4* WIH1Tu4  = (uint4*)(ws + WIH1T);
  unsigned* GWu   = (unsigned*)(ws + GWR);
  unsigned* flg   = (unsigned*)(ws + PCF);
  uint4* DWu4     = (uint4*)(ws + Y0OF);   // decoder transposed dWih1 (after R)
  unsigned genF = 0;
  const int bfm = detect_bf16(p.x);
  const int enc_act = (w < 128);
  const int d = (w >> 6) & 1, b = w & 63;
  const int R0 = t >> 1, hs = t & 1, swz = R0 & 7;

  uint4 wreg3[3][16];   // rows R0, R0+256, R0+512 (K-half hs): 48 uint4

  // ============================ E0 prep ====================================
  {
    if (w == 0) {                         // reset producer/consumer flags
      for (int i = t; i < 8192; i += THR) flg[i] = 0u;
    }
    if (enc_act) {
      const void* whh0 = bfm ? (const void*)((const unsigned short*)p.eWhh0 + (size_t)d * 262144)
                             : (const void*)((const float*)p.eWhh0 + (size_t)d * 262144);
#pragma unroll
      for (int kk = 0; kk < 16; ++kk) {
        wreg3[0][kk] = ldw8(whh0, (size_t)R0 * 256 + (size_t)hs * 128 + kk * 8, bfm);
        wreg3[1][kk] = ldw8(whh0, (size_t)(256 + R0) * 256 + (size_t)hs * 128 + kk * 8, bfm);
        wreg3[2][kk] = ldw8(whh0, (size_t)(512 + R0) * 256 + (size_t)hs * 128 + kk * 8, bfm);
      }
#pragma unroll
      for (int i = 0; i < 16; ++i) {      // WLDS rows 768-1023, swizzled
        int idx = t + i * 512;
        int row = idx >> 5, j = idx & 31;
        WLDSu4[row * 32 + (j ^ (row & 7))] =
            ldw8(whh0, (size_t)(768 + row) * 256 + j * 8, bfm);
      }
#pragma unroll
      for (int q = 0; q < 2; ++q) {
        PREB[t + q * 512]  = ldin(p.eB0,   d * 1024 + t + q * 512, bfm);
        PREWf[t + q * 512] = ldin(p.eWih0, d * 1024 + t + q * 512, bfm);
        XROW[t + q * 512]  = ldin(p.x, (size_t)b * 1024 + t + q * 512, bfm);
      }
      if (t < 256) H16[t] = 0u;           // both h buffers
    } else {
      // idle WGs pre-transpose Wih1 during E0 (consumed by producers in E1;
      // visibility via the two fenced gbars before first use)
#pragma unroll
      for (int q = 0; q < 2; ++q) {
        int idx = (w - 128) * 1024 + q * 512 + t;   // 131072 uint4 total
        int dd = idx >> 16, rem = idx & 65535;
        int kc = rem >> 10, row = rem & 1023;
        WIH1Tu4[idx] = ldw8(p.eWih1, (size_t)dd * 524288 + (size_t)row * 512 + kc * 8, bfm);
      }
    }
  }
  gbar(ctrs, ++genF);

  // ====================== E0: 1024 steps, ONE sync, 0 global loads =========
  if (enc_act) {
    float cc = 0.f;
    const uint4* wl = WLDSu4 + R0 * 32;
    // loop-invariant cell constants hoisted to registers
    const float pb0 = PREB[R0],       pb1 = PREB[256 + R0];
    const float pb2 = PREB[512 + R0], pb3 = PREB[768 + R0];
    const float pw0 = PREWf[R0],       pw1 = PREWf[256 + R0];
    const float pw2 = PREWf[512 + R0], pw3 = PREWf[768 + R0];
    int pp = 0;
    unsigned ppw = 0;                    // deferred y0 store (one step late)
    int ptt = -1;
    for (int st = 0; st < 1024; ++st) {
      const int tt = d ? (1023 - st) : st;
      // previous step's y0 store: issued just after the barrier -> its L2 ack
      // is a full step away from the next vmcnt(0) drain (no stall)
      if (ptt >= 0 && (t & 3) == 0)
        y0w[(size_t)ptt * 16384 + (size_t)b * 256 + d * 128 + (t >> 2)] = ppw;
      float xv = XROW[tt];
      // 8 independent FMA chains (two K-half sub-chains per gate row)
      float s0a = 0.f, s0b = 0.f, s1a = 0.f, s1b = 0.f;
      float s2a = 0.f, s2b = 0.f, s3a = 0.f, s3b = 0.f;
      const unsigned* hb = H16 + pp * 128 + hs * 64;
#pragma unroll
      for (int i = 0; i < 8; ++i) {
        uint4 ha = *(const uint4*)(hb + i * 4);
        uint4 hc = *(const uint4*)(hb + (8 + i) * 4);
        s0a = dot1(s0a, ha, wreg3[0][i]);  s0b = dot1(s0b, hc, wreg3[0][8 + i]);
        s1a = dot1(s1a, ha, wreg3[1][i]);  s1b = dot1(s1b, hc, wreg3[1][8 + i]);
        s2a = dot1(s2a, ha, wreg3[2][i]);  s2b = dot1(s2b, hc, wreg3[2][8 + i]);
        s3a = dot1(s3a, ha, wl[(hs * 16 + i) ^ swz]);
        s3b = dot1(s3b, hc, wl[(hs * 16 + 8 + i) ^ swz]);
      }
      float s0 = s0a + s0b, s1 = s1a + s1b, s2 = s2a + s2b, s3 = s3a + s3b;
      s0 += __shfl_xor(s0, 1, 64);
      s1 += __shfl_xor(s1, 1, 64);
      s2 += __shfl_xor(s2, 1, 64);
      s3 += __shfl_xor(s3, 1, 64);
      // cell: both lanes of the pair, redundantly (no divergence)
      float gi = s0 + pb0 + xv * pw0;
      float gf = s1 + pb1 + xv * pw1;
      float gg = s2 + pb2 + xv * pw2;
      float go = s3 + pb3 + xv * pw3;
      float cn = sigm(gf) * cc + sigm(gi) * ftanh(gg);
      float hn = sigm(go) * ftanh(cn);
      cc = cn;
      unsigned hu = (unsigned)f2h_u(hn);
      unsigned hnn = __shfl_down(hu, 2, 64);          // col pair partner
      ppw = hu | (hnn << 16);
      ptt = tt;
      if (hs == 0) ((unsigned short*)(H16 + (pp ^ 1) * 128))[R0] = (unsigned short)hu;
      if (st == 1023 && hs == 0) ws[ECL0 + d * 16384 + b * 256 + R0] = cn;
      __syncthreads();
      pp ^= 1;
    }
    // tail: final y0 row (before the publishing gbar)
    if ((t & 3) == 0)
      y0w[(size_t)ptt * 16384 + (size_t)b * 256 + d * 128 + (t >> 2)] = ppw;
  }
  gbar(ctrs, ++genF);   // y0 / ECL0 visible

  // ============================ E1 prep ====================================
  {
    if (enc_act) {
      const void* whh1 = bfm ? (const void*)((const unsigned short*)p.eWhh1 + (size_t)d * 262144)
                             : (const void*)((const float*)p.eWhh1 + (size_t)d * 262144);
#pragma unroll
      for (int kk = 0; kk < 16; ++kk) {
        wreg3[0][kk] = ldw8(whh1, (size_t)R0 * 256 + (size_t)hs * 128 + kk * 8, bfm);
        wreg3[1][kk] = ldw8(whh1, (size_t)(256 + R0) * 256 + (size_t)hs * 128 + kk * 8, bfm);
        wreg3[2][kk] = ldw8(whh1, (size_t)(512 + R0) * 256 + (size_t)hs * 128 + kk * 8, bfm);
      }
#pragma unroll
      for (int i = 0; i < 16; ++i) {
        int idx = t + i * 512;
        int row = idx >> 5, j = idx & 31;
        WLDSu4[row * 32 + (j ^ (row & 7))] =
            ldw8(whh1, (size_t)(768 + row) * 256 + j * 8, bfm);
      }
#pragma unroll
      for (int q = 0; q < 2; ++q)
        PREB[t + q * 512] = ldin(p.eB1, d * 1024 + t + q * 512, bfm);
      if (t < 256) H16[t] = 0u;
    }
  }
  gbar(ctrs, ++genF);   // W' + y0 + flags visible

  // ====================== E1: consumers + producers ========================
  if (enc_act) {
    float cc = 0.f;
    const uint4* wl = WLDSu4 + R0 * 32;
    const float pb0 = PREB[R0],       pb1 = PREB[256 + R0];
    const float pb2 = PREB[512 + R0], pb3 = PREB[768 + R0];
    int pp = 0;
    for (int st = 0; st < 1024; ++st) {
      const int win = st >> 3, sl = st & 7;
      if (sl == 0) {
        if (t == 0) {
          while (__hip_atomic_load(&flg[w * 64], __ATOMIC_RELAXED,
                                   __HIP_MEMORY_SCOPE_AGENT) < (unsigned)(win + 1)) {
            __builtin_amdgcn_s_sleep(1);
          }
        }
        __atomic_signal_fence(__ATOMIC_ACQUIRE);
        __syncthreads();
      }
      const unsigned gb = (unsigned)w * 8192 + (unsigned)(win & 1) * 4096 + (unsigned)sl * 512;
      unsigned gw0 = __hip_atomic_load(&GWu[gb + R0],       __ATOMIC_RELAXED, __HIP_MEMORY_SCOPE_AGENT);
      unsigned gw1 = __hip_atomic_load(&GWu[gb + 256 + R0], __ATOMIC_RELAXED, __HIP_MEMORY_SCOPE_AGENT);
      float s0a = 0.f, s0b = 0.f, s1a = 0.f, s1b = 0.f;
      float s2a = 0.f, s2b = 0.f, s3a = 0.f, s3b = 0.f;
      const unsigned* hb = H16 + pp * 128 + hs * 64;
#pragma unroll
      for (int i = 0; i < 8; ++i) {
        uint4 ha = *(const uint4*)(hb + i * 4);
        uint4 hc = *(const uint4*)(hb + (8 + i) * 4);
        s0a = dot1(s0a, ha, wreg3[0][i]);  s0b = dot1(s0b, hc, wreg3[0][8 + i]);
        s1a = dot1(s1a, ha, wreg3[1][i]);  s1b = dot1(s1b, hc, wreg3[1][8 + i]);
        s2a = dot1(s2a, ha, wreg3[2][i]);  s2b = dot1(s2b, hc, wreg3[2][8 + i]);
        s3a = dot1(s3a, ha, wl[(hs * 16 + i) ^ swz]);
        s3b = dot1(s3b, hc, wl[(hs * 16 + 8 + i) ^ swz]);
      }
      float s0 = s0a + s0b, s1 = s1a + s1b, s2 = s2a + s2b, s3 = s3a + s3b;
      s0 += __shfl_xor(s0, 1, 64);
      s1 += __shfl_xor(s1, 1, 64);
      s2 += __shfl_xor(s2, 1, 64);
      s3 += __shfl_xor(s3, 1, 64);
      float gi = s0 + pb0 + hf2f((unsigned short)(gw0 & 0xffffu));
      float gf = s1 + pb1 + hf2f((unsigned short)(gw1 & 0xffffu));
      float gg = s2 + pb2 + hf2f((unsigned short)(gw0 >> 16));
      float go = s3 + pb3 + hf2f((unsigned short)(gw1 >> 16));
      float cn = sigm(gf) * cc + sigm(gi) * ftanh(gg);
      float hn = sigm(go) * ftanh(cn);
      cc = cn;
      unsigned hu = (unsigned)f2h_u(hn);
      unsigned hnn = __shfl_down(hu, 2, 64);
      if (st == 1023) {
        if ((t & 3) == 0)
          EHL1u[d * 8192 + b * 128 + (t >> 2)] = hu | (hnn << 16);
        if (hs == 0) ws[ECL1 + d * 16384 + b * 256 + R0] = cn;
      }
      if (hs == 0) ((unsigned short*)(H16 + (pp ^ 1) * 128))[R0] = (unsigned short)hu;
      __syncthreads();
      if (sl == 7 && t == 0)
        __hip_atomic_store(&flg[w * 64 + 32], (unsigned)(win + 1),
                           __ATOMIC_RELAXED, __HIP_MEMORY_SCOPE_AGENT);
      pp ^= 1;
    }
  } else {
    // -------- producer: GW = y0 @ Wih1^T, window-by-window -----------------
    const int chain = w - 128, dp = chain >> 6, bp = chain & 63;
    const uint4* Wt = WIH1Tu4 + (size_t)dp * 65536;
    uint4* YWu4 = (uint4*)smem;          // [8][64] uint4 (WLDS unused here)
    for (int win = 0; win < 128; ++win) {
      if (win >= 2) {
        if (t == 0) {
          while (__hip_atomic_load(&flg[chain * 64 + 32], __ATOMIC_RELAXED,
                                   __HIP_MEMORY_SCOPE_AGENT) < (unsigned)(win - 1)) {
            __builtin_amdgcn_s_sleep(1);
          }
        }
        __syncthreads();
      }
      {
        int s = t >> 6, kcc = t & 63;
        int tw = dp ? (1023 - (win * 8 + s)) : (win * 8 + s);
        YWu4[s * 64 + kcc] =
            *(const uint4*)(y0w + (size_t)tw * 16384 + (size_t)bp * 256 + kcc * 4);
      }
      __syncthreads();
      float a0[8], a1[8];
#pragma unroll
      for (int s = 0; s < 8; ++s) { a0[s] = 0.f; a1[s] = 0.f; }
      for (int kc = 0; kc < 64; ++kc) {
        uint4 w0 = Wt[kc * 1024 + t];
        uint4 w1 = Wt[kc * 1024 + 512 + t];
#pragma unroll
        for (int s = 0; s < 8; ++s) {
          uint4 yv = YWu4[s * 64 + kc];
          a0[s] = dot1(a0[s], yv, w0);
          a1[s] = dot1(a1[s], yv, w1);
        }
      }
      const unsigned gb = (unsigned)chain * 8192 + (unsigned)(win & 1) * 4096;
#pragma unroll
      for (int s = 0; s < 8; ++s) {
        unsigned pw = (unsigned)f2h_u(a0[s]) | ((unsigned)f2h_u(a1[s]) << 16);
        __hip_atomic_store(&GWu[gb + s * 512 + t], pw,
                           __ATOMIC_RELAXED, __HIP_MEMORY_SCOPE_AGENT);
      }
      __syncthreads();                   // drains vmcnt: sc1 stores at IC
      if (t == 0)
        __hip_atomic_store(&flg[chain * 64], (unsigned)(win + 1),
                           __ATOMIC_RELAXED, __HIP_MEMORY_SCOPE_AGENT);
    }
  }
  gbar(ctrs, ++genF);   // EHL1/ECL1 visible

  // ===================== decoder recurrent consts R ========================
  {
    unsigned* AH0 = (unsigned*)smem;
    float* part = (float*)(smem + 33792);
    const int m = w >> 6, wl6 = w & 63;
    const void* whh;
    if (bfm) whh = (m < 2) ? (const void*)((const unsigned short*)p.dWhh0 + (size_t)m * 262144)
                           : (const void*)((const unsigned short*)p.dWhh1 + (size_t)(m - 2) * 262144);
    else     whh = (m < 2) ? (const void*)((const float*)p.dWhh0 + (size_t)m * 262144)
                           : (const void*)((const float*)p.dWhh1 + (size_t)(m - 2) * 262144);
    const void* bb;
    if (bfm) bb = (m < 2) ? (const void*)((const unsigned short*)p.dB0 + m * 1024)
                          : (const void*)((const unsigned short*)p.dB1 + (m - 2) * 1024);
    else     bb = (m < 2) ? (const void*)((const float*)p.dB0 + m * 1024)
                          : (const void*)((const float*)p.dB1 + (m - 2) * 1024);
    if (m == 0)      stage_u128(AH0, y0w + (size_t)1023 * 16384, 256, 0);
    else if (m == 1) stage_u128(AH0, y0w, 256, 128);
    else             stage_u128(AH0, EHL1u + (m - 2) * 8192, 128, 0);
    __syncthreads();
    float* dst = ws + ROF + m * 65536;
    for (int pass = 0; pass < 2; ++pass) {
      const int rowbase = wl6 * 16 + pass * 8;
      uint4 wrA[2][4];
      load_w16_rows(wrA, whh, rowbase, bfm);
      float4 acc[8];
#pragma unroll
      for (int e = 0; e < 8; ++e) acc[e] = make_float4(0.f, 0.f, 0.f, 0.f);
      dot2_t4(acc, AH0, wrA);
      reduce_R(acc, part, dst, bb, rowbase, bfm);
    }
  }
  gbar(ctrs, ++genF);   // ROF visible

  // ============================ decoder prep ===============================
  {
    int idx = w * 512 + t;               // transposed fp16 dWih1 (dead y0 head)
    int dd = idx >> 16, rem = idx & 65535;
    int kc = rem >> 10, row = rem & 1023;
    DWu4[idx] = ldw8(p.dWih1, (size_t)dd * 524288 + (size_t)row * 512 + kc * 8, bfm);
  }
  float r1i = 0.f, r1f = 0.f, r1g = 0.f, r1o = 0.f, coldc = 0.f, fwc = 0.f, fcb = 0.f;
  {
    float* R0L  = (float*)smem;          // [2][1024]
    float* WI0L = (float*)(smem + 8192); // [2][1024]
    float* C0L  = (float*)(smem + 16384);// [2][256]
    if (w < 64) {
      const int bq = w;
#pragma unroll
      for (int i = 0; i < 4; ++i) {
        int r = t + i * THR;
        int dz = r >> 10, rr = r & 1023;
        R0L[r]  = ws[ROF + dz * 65536 + (size_t)bq * 1024 + rr];
        WI0L[r] = ldin(p.dWih0, dz * 1024 + rr, bfm);
      }
      C0L[t >= 512 ? 0 : t] = ws[ECL0 + (t >> 8) * 16384 + (size_t)bq * 256 + (t & 255)];
      const int dd2 = t >> 8, col = t & 255;
      r1i = ws[ROF + (2 + dd2) * 65536 + (size_t)bq * 1024 +       col];
      r1f = ws[ROF + (2 + dd2) * 65536 + (size_t)bq * 1024 + 256 + col];
      r1g = ws[ROF + (2 + dd2) * 65536 + (size_t)bq * 1024 + 512 + col];
      r1o = ws[ROF + (2 + dd2) * 65536 + (size_t)bq * 1024 + 768 + col];
      coldc = ws[ECL1 + dd2 * 16384 + (size_t)bq * 256 + col];
      fwc = ldin(p.fcW, dd2 * 256 + col, bfm);
      fcb = ldin(p.fcb, 0, bfm);
    }
  }
  gbar(ctrs, ++genF);   // DW' visible

  // ===================== decoder loop: one WG per batch ====================
  if (w < 64) {
    const int bq = w;
    float* R0L  = (float*)smem;
    float* WI0L = (float*)(smem + 8192);
    float* C0L  = (float*)(smem + 16384);
    unsigned* ZV = (unsigned*)(smem + 18432);
    const int dd2 = t >> 8, col = t & 255;
    const uint4* DWt = DWu4 + (size_t)dd2 * 65536;

    {
      float gi = R0L[dd2 * 1024 +       col];
      float gf = R0L[dd2 * 1024 + 256 + col];
      float gg = R0L[dd2 * 1024 + 512 + col];
      float go = R0L[dd2 * 1024 + 768 + col];
      float cold = C0L[dd2 * 256 + col];
      float cn = sigm(gf) * cold + sigm(gi) * ftanh(gg);
      float hz = sigm(go) * ftanh(cn);
      ((unsigned short*)ZV)[t] = f2h_u(hz);
    }
    __syncthreads();

    float yp1 = 3.0e38f, yp2 = -3.0e38f;
    for (int st = 0; st < 1024; ++st) {
      float ai = 0.f, af = 0.f, ag = 0.f, ao = 0.f;
      for (int kc = 0; kc < 64; ++kc) {
        uint4 zv = *(const uint4*)(ZV + kc * 4);
        uint4 w0 = DWt[kc * 1024 +       col];
        uint4 w1 = DWt[kc * 1024 + 256 + col];
        uint4 w2 = DWt[kc * 1024 + 512 + col];
        uint4 w3 = DWt[kc * 1024 + 768 + col];
        ai = dot1(ai, zv, w0);
        af = dot1(af, zv, w1);
        ag = dot1(ag, zv, w2);
        ao = dot1(ao, zv, w3);
      }
      float gi = ai + r1i, gf = af + r1f, gg = ag + r1g, go = ao + r1o;
      float cn = sigm(gf) * coldc + sigm(gi) * ftanh(gg);
      float h1 = sigm(go) * ftanh(cn);
      GF[t] = h1 * fwc;
      __syncthreads();
      if (t < 64) {
        const float* q = GF + t;
        GF[t] = ((q[0] + q[64]) + (q[128] + q[192])) +
                ((q[256] + q[320]) + (q[384] + q[448]));
      }
      __syncthreads();
      if (t == 0) {
        float yy = fcb;
        for (int i = 0; i < 64; ++i) yy += GF[i];
        YL[0] = yy;
      }
      __syncthreads();
      float ynew = YL[0];
      if (t == 0) stout(p.out, (size_t)bq * 1024 + st, ynew, bfm);
      if (ynew == yp1) {
        for (int t2 = st + 1 + t; t2 < 1024; t2 += THR)
          stout(p.out, (size_t)bq * 1024 + t2, ynew, bfm);
        break;
      }
      if (ynew == yp2) {
        for (int t2 = st + 1 + t; t2 < 1024; t2 += THR)
          stout(p.out, (size_t)bq * 1024 + t2, ((t2 - st) & 1) ? yp1 : ynew, bfm);
        break;
      }
      yp2 = yp1; yp1 = ynew;
      if (st < 1023) {
        __syncthreads();
        float gi2 = ynew * WI0L[dd2 * 1024 +       col] + R0L[dd2 * 1024 +       col];
        float gf2 = ynew * WI0L[dd2 * 1024 + 256 + col] + R0L[dd2 * 1024 + 256 + col];
        float gg2 = ynew * WI0L[dd2 * 1024 + 512 + col] + R0L[dd2 * 1024 + 512 + col];
        float go2 = ynew * WI0L[dd2 * 1024 + 768 + col] + R0L[dd2 * 1024 + 768 + col];
        float cold = C0L[dd2 * 256 + col];
        float cn2 = sigm(gf2) * cold + sigm(gi2) * ftanh(gg2);
        float hz = sigm(go2) * ftanh(cn2);
        ((unsigned short*)ZV)[t] = f2h_u(hz);
        __syncthreads();
      }
    }
  }
}

// diagnostic: if ws too small, encode ws_size (MB) into the output signature
__global__ void fill_sig(unsigned short* out, int n, float val) {
  int i = blockIdx.x * 256 + threadIdx.x;
  __hip_bfloat16 b = __float2bfloat16(val);
  if (i < n) out[i] = *reinterpret_cast<unsigned short*>(&b);
}

extern "C" void kernel_launch(void* const* d_in, const int* in_sizes, int n_in,
                              void* d_out, int out_size, void* d_ws, size_t ws_size,
                              hipStream_t stream) {
  (void)in_sizes; (void)n_in;
  if (ws_size < WS_REQ_BYTES) {
    float sig = 2048.0f + (float)(ws_size >> 20);
    fill_sig<<<(out_size + 255) / 256, 256, 0, stream>>>(
        (unsigned short*)d_out, out_size, sig);
    return;
  }
  hipMemsetAsync(d_ws, 0, 8192, stream);  // zero barrier counters

  SeqParams p;
  p.x     = d_in[0];
  p.eWih0 = d_in[1];
  p.eWhh0 = d_in[2];
  p.eB0   = d_in[3];
  p.eWih1 = d_in[4];
  p.eWhh1 = d_in[5];
  p.eB1   = d_in[6];
  p.dWih0 = d_in[7];
  p.dWhh0 = d_in[8];
  p.dB0   = d_in[9];
  p.dWih1 = d_in[10];
  p.dWhh1 = d_in[11];
  p.dB1   = d_in[12];
  p.fcW   = d_in[13];
  p.fcb   = d_in[14];
  p.out   = d_out;
  p.ws    = (float*)d_ws;
  p.ctrs  = (unsigned*)d_ws;

  seq2seq_kernel<<<dim3(NWG), dim3(THR), 0, stream>>>(p);
}